// Round 4
// baseline (149.135 us; speedup 1.0000x reference)
//
#include <hip/hip_runtime.h>
#include <hip/hip_bf16.h>
#include <math.h>

#define B_SZ 16
#define L_SEQ 128
#define D_M 32
#define N_ST 8
#define HW 65536           // 256*256
#define NROWS (B_SZ * 128) // 2048 (b,c) rows
#define NCHUNK 4           // chunks per row for kmax

typedef float vfloat4 __attribute__((ext_vector_type(4)));

// Device-global scratch
__device__ float g_part[NROWS * NCHUNK];       // partial maxima
__device__ float g_y0[B_SZ * D_M * L_SEQ];     // forward branch y, fwd orientation
__device__ float g_y1[B_SZ * D_M * L_SEQ];     // backward branch y, already flipped back

__device__ __forceinline__ float silu_acc(float x) {
    return x / (1.f + expf(-x));
}
__device__ __forceinline__ float softplusf(float x) {
    return (x > 20.f) ? x : log1pf(expf(x));
}

// 8-lane sum via DPP (no LDS): xor1, xor2 within quad, then mirror across quads.
__device__ __forceinline__ float sum8_dpp(float y) {
    float t;
    t = __int_as_float(__builtin_amdgcn_mov_dpp(__float_as_int(y), 0xB1, 0xF, 0xF, true));  // quad_perm [1,0,3,2]
    y += t;
    t = __int_as_float(__builtin_amdgcn_mov_dpp(__float_as_int(y), 0x4E, 0xF, 0xF, true));  // quad_perm [2,3,0,1]
    y += t;
    t = __int_as_float(__builtin_amdgcn_mov_dpp(__float_as_int(y), 0x141, 0xF, 0xF, true)); // row_half_mirror
    y += t;
    return y;
}

// ---------------- K1: partial max over quarter-rows ----------------
__global__ __launch_bounds__(256) void kmax(const float* __restrict__ x) {
    const int blk = blockIdx.x;                 // 0..8191
    const vfloat4* __restrict__ p =
        reinterpret_cast<const vfloat4*>(x) + (size_t)blk * 4096;
    const int t = threadIdx.x;
    float m0 = -INFINITY, m1 = -INFINITY, m2 = -INFINITY, m3 = -INFINITY;
#pragma unroll
    for (int i = 0; i < 4096; i += 1024) {
        vfloat4 v0 = p[i + t];
        vfloat4 v1 = p[i + t + 256];
        vfloat4 v2 = p[i + t + 512];
        vfloat4 v3 = p[i + t + 768];
        m0 = fmaxf(m0, fmaxf(fmaxf(v0.x, v0.y), fmaxf(v0.z, v0.w)));
        m1 = fmaxf(m1, fmaxf(fmaxf(v1.x, v1.y), fmaxf(v1.z, v1.w)));
        m2 = fmaxf(m2, fmaxf(fmaxf(v2.x, v2.y), fmaxf(v2.z, v2.w)));
        m3 = fmaxf(m3, fmaxf(fmaxf(v3.x, v3.y), fmaxf(v3.z, v3.w)));
    }
    float m = fmaxf(fmaxf(m0, m1), fmaxf(m2, m3));
#pragma unroll
    for (int off = 32; off >= 1; off >>= 1)
        m = fmaxf(m, __shfl_xor(m, off));
    __shared__ float sm[4];
    if ((threadIdx.x & 63) == 0) sm[threadIdx.x >> 6] = m;
    __syncthreads();
    if (threadIdx.x == 0)
        g_part[blk] = fmaxf(fmaxf(sm[0], sm[1]), fmaxf(sm[2], sm[3]));
}

__device__ __forceinline__ float row_max(int row) {
    const int r4 = row * NCHUNK;
    return fmaxf(fmaxf(g_part[r4], g_part[r4 + 1]),
                 fmaxf(g_part[r4 + 2], g_part[r4 + 3]));
}

// ---------------- K2: per (batch, direction): prelude + conv + SSM scan ----------------
__global__ __launch_bounds__(512) void kbranch(
    const float* __restrict__ w1,  const float* __restrict__ b1,
    const float* __restrict__ lng, const float* __restrict__ lnb,
    const float* __restrict__ Win,
    const float* __restrict__ cw_f, const float* __restrict__ cb_f,
    const float* __restrict__ xp_f, const float* __restrict__ dtw_f,
    const float* __restrict__ dtb_f, const float* __restrict__ Al_f,
    const float* __restrict__ Dp_f,
    const float* __restrict__ cw_b, const float* __restrict__ cb_b,
    const float* __restrict__ xp_b, const float* __restrict__ dtw_b,
    const float* __restrict__ dtb_b, const float* __restrict__ Al_b,
    const float* __restrict__ Dp_b) {
    const int b = blockIdx.x >> 1;
    const int beta = blockIdx.x & 1;
    const int tid = threadIdx.x;

    const float* cw  = beta ? cw_b  : cw_f;
    const float* cb  = beta ? cb_b  : cb_f;
    const float* xp  = beta ? xp_b  : xp_f;
    const float* dtw = beta ? dtw_b : dtw_f;
    const float* dtb = beta ? dtb_b : dtb_f;
    const float* Al  = beta ? Al_b  : Al_f;
    const float* Dp  = beta ? Dp_b  : Dp_f;
    float* yout = beta ? g_y1 : g_y0;

    // Manually-overlaid LDS (62 KB)
    __shared__ float S[15520];
    float* sh  = S;                 // [128][33]  h         (phase 1-2) = 4224
    float* sy  = S;                 // [32][128]  y         (scan+)     = 4096  (overlays sh)
    float* sWx = S + 4224;          // [32][32]   Win x-half(phase 2)   = 1024
    float* sxp = S + 4224;          // [18][33]   xproj pad (phase 4)   = 594   (overlays sWx)
    float* sdt = S + 4224 + 594;    // [128][2]   dt        (phase 4-5) = 256
    float* sx  = S + 5248;          // [32][128]  x         (conv)      = 4096
    float* sdl = S + 5248;          // [128][32]  delta     (scan)      = 4096  (overlays sx)
    float* su  = S + 9344;          // [32][129]  u         (conv->end) = 4128
    float* sB  = S + 13472;         // [128][8]                          = 1024
    float* sC  = S + 14496;         // [128][8]                          = 1024

    // Phase 1: h = LN(s*w1+b1); also stage Win x-half
    for (int i = tid; i < 1024; i += 512) sWx[i] = Win[i];
    if (tid < 128) {
        const int l = tid;
        const float s = row_max(b * L_SEQ + l);
        float h[D_M];
        float mean = 0.f;
#pragma unroll
        for (int d = 0; d < D_M; d++) { h[d] = s * w1[d] + b1[d]; mean += h[d]; }
        mean *= (1.f / D_M);
        float var = 0.f;
#pragma unroll
        for (int d = 0; d < D_M; d++) { float t = h[d] - mean; var += t * t; }
        var *= (1.f / D_M);
        const float rs = rsqrtf(var + 1e-5f);
#pragma unroll
        for (int d = 0; d < D_M; d++)
            sh[l * 33 + d] = (h[d] - mean) * rs * lng[d] + lnb[d];
    }
    __syncthreads();

    // Phase 2: x-half GEMV, stored pre-flipped for backward branch
    for (int i = tid; i < 4096; i += 512) {
        const int e = i >> 7, l = i & 127;
        float acc = 0.f;
#pragma unroll
        for (int d = 0; d < D_M; d++) acc += sh[l * 33 + d] * sWx[e * 32 + d];
        sx[e * 128 + (beta ? 127 - l : l)] = acc;
    }
    __syncthreads();

    // Phase 3: causal depthwise conv(4) + SiLU; also stage padded xproj
    for (int i = tid; i < 576; i += 512) {
        const int r = i >> 5, d = i & 31;
        sxp[r * 33 + d] = xp[i];
    }
    for (int i = tid; i < 4096; i += 512) {
        const int d = i >> 7, l = i & 127;
        float acc = cb[d];
#pragma unroll
        for (int k = 0; k < 4; k++) {
            const int j = l - 3 + k;
            if (j >= 0) acc += cw[d * 4 + k] * sx[d * 128 + j];
        }
        su[d * 129 + l] = silu_acc(acc);
    }
    __syncthreads();

    // Phase 4: x_dbl = u^T @ xproj^T -> dt, B, C
    for (int i = tid; i < L_SEQ * 18; i += 512) {
        const int l = i / 18, r = i - l * 18;
        float acc = 0.f;
#pragma unroll
        for (int d = 0; d < D_M; d++) acc += su[d * 129 + l] * sxp[r * 33 + d];
        if (r < 2)       sdt[l * 2 + r] = acc;
        else if (r < 10) sB[l * 8 + (r - 2)] = acc;
        else             sC[l * 8 + (r - 10)] = acc;
    }
    __syncthreads();

    // Phase 5: delta = softplus(dt @ dtw^T + dtb)  (overwrites sx)
    for (int i = tid; i < L_SEQ * D_M; i += 512) {
        const int l = i >> 5, d = i & 31;
        const float t = sdt[l * 2 + 0] * dtw[d * 2 + 0] +
                        sdt[l * 2 + 1] * dtw[d * 2 + 1] + dtb[d];
        sdl[l * 32 + d] = softplusf(t);
    }
    __syncthreads();

    // Phase 6: sequential scan, thread = (d, n); waves 4-7 idle; sy overlays sh
    if (tid < 256) {
        const int d = tid >> 3, n = tid & 7;
        const float A = -expf(Al[d * 8 + n]);
        const float Dd = Dp[d];
        float hst = 0.f;
        for (int l = 0; l < L_SEQ; l++) {
            const float dl = sdl[l * 32 + d];
            const float ul = su[d * 129 + l];
            const float dA = expf(dl * A);
            hst = dA * hst + (dl * ul) * sB[l * 8 + n];
            const float y = sum8_dpp(hst * sC[l * 8 + n]);
            if (n == 0) sy[d * 128 + l] = y + Dd * ul;
        }
    }
    __syncthreads();

    // Phase 7: store y (backward branch flipped back to forward orientation)
    for (int i = tid; i < 4096; i += 512) {
        const int d = i >> 7, l = i & 127;
        const int gl = beta ? (127 - l) : l;
        yout[(b * D_M + d) * L_SEQ + gl] = sy[d * 128 + l];
    }
}

// ---------------- K3: z GEMV + combine + LN/2 + out_proj + w2 + sigmoid ----------------
__global__ __launch_bounds__(128) void kfinal(
    const float* __restrict__ w1,  const float* __restrict__ b1,
    const float* __restrict__ lng, const float* __restrict__ lnb,
    const float* __restrict__ Win,
    const float* __restrict__ ng,  const float* __restrict__ nb,
    const float* __restrict__ Wout, const float* __restrict__ w2,
    const float* __restrict__ b2,  float* __restrict__ out) {
    const int b = blockIdx.x;
    const int l = threadIdx.x;
    __shared__ float sWz[32 * 32];
    __shared__ float sWo[32 * 32];
    for (int i = l; i < 1024; i += 128) {
        sWz[i] = Win[1024 + i];   // z-half rows of in_proj
        sWo[i] = Wout[i];
    }
    __syncthreads();

    // prelude h (recomputed, trivial)
    const float s = row_max(b * L_SEQ + l);
    float h[D_M];
    float mean = 0.f;
#pragma unroll
    for (int d = 0; d < D_M; d++) { h[d] = s * w1[d] + b1[d]; mean += h[d]; }
    mean *= (1.f / D_M);
    float var = 0.f;
#pragma unroll
    for (int d = 0; d < D_M; d++) { float t = h[d] - mean; var += t * t; }
    var *= (1.f / D_M);
    float rs = rsqrtf(var + 1e-5f);
#pragma unroll
    for (int d = 0; d < D_M; d++) h[d] = (h[d] - mean) * rs * lng[d] + lnb[d];

    // v[d] = (y_f + y_b)[d][l] * silu(z[d][l]);  z = h @ Wz^T
    float v[D_M];
#pragma unroll
    for (int d = 0; d < D_M; d++) {
        float z = 0.f;
#pragma unroll
        for (int k = 0; k < D_M; k++) z += h[k] * sWz[d * 32 + k];
        const float yc = g_y0[(b * D_M + d) * L_SEQ + l] +
                         g_y1[(b * D_M + d) * L_SEQ + l];
        v[d] = yc * silu_acc(z);
    }

    // LN / 2
    mean = 0.f;
#pragma unroll
    for (int d = 0; d < D_M; d++) mean += v[d];
    mean *= (1.f / D_M);
    var = 0.f;
#pragma unroll
    for (int d = 0; d < D_M; d++) { float t = v[d] - mean; var += t * t; }
    var *= (1.f / D_M);
    rs = rsqrtf(var + 1e-5f);
#pragma unroll
    for (int d = 0; d < D_M; d++)
        v[d] = ((v[d] - mean) * rs * ng[d] + nb[d]) * 0.5f;

    // out_proj then w2 dot, sigmoid
    float acc = 0.f;
    for (int o = 0; o < D_M; o++) {
        float t = 0.f;
#pragma unroll
        for (int d = 0; d < D_M; d++) t += v[d] * sWo[o * 32 + d];
        acc += t * w2[o];
    }
    acc += b2[0];
    out[b * L_SEQ + l] = 1.f / (1.f + expf(-acc));
}

extern "C" void kernel_launch(void* const* d_in, const int* in_sizes, int n_in,
                              void* d_out, int out_size, void* d_ws, size_t ws_size,
                              hipStream_t stream) {
    const float* x        = (const float*)d_in[0];
    const float* w1       = (const float*)d_in[1];
    const float* b1       = (const float*)d_in[2];
    const float* ln_g     = (const float*)d_in[3];
    const float* ln_b     = (const float*)d_in[4];
    const float* in_proj  = (const float*)d_in[5];
    const float* cw_f     = (const float*)d_in[6];
    const float* cb_f     = (const float*)d_in[7];
    const float* xp_f     = (const float*)d_in[8];
    const float* dtw_f    = (const float*)d_in[9];
    const float* dtb_f    = (const float*)d_in[10];
    const float* Al_f     = (const float*)d_in[11];
    const float* Dp_f     = (const float*)d_in[12];
    const float* cw_b     = (const float*)d_in[13];
    const float* cb_b     = (const float*)d_in[14];
    const float* xp_b     = (const float*)d_in[15];
    const float* dtw_b    = (const float*)d_in[16];
    const float* dtb_b    = (const float*)d_in[17];
    const float* Al_b     = (const float*)d_in[18];
    const float* Dp_b     = (const float*)d_in[19];
    const float* norm_g   = (const float*)d_in[20];
    const float* norm_b   = (const float*)d_in[21];
    const float* Wout     = (const float*)d_in[22];
    const float* w2       = (const float*)d_in[23];
    const float* b2       = (const float*)d_in[24];

    kmax<<<NROWS * NCHUNK, 256, 0, stream>>>(x);
    kbranch<<<B_SZ * 2, 512, 0, stream>>>(w1, b1, ln_g, ln_b, in_proj,
                                          cw_f, cb_f, xp_f, dtw_f, dtb_f, Al_f, Dp_f,
                                          cw_b, cb_b, xp_b, dtw_b, dtb_b, Al_b, Dp_b);
    kfinal<<<B_SZ, 128, 0, stream>>>(w1, b1, ln_g, ln_b, in_proj,
                                     norm_g, norm_b, Wout, w2, b2, (float*)d_out);
}

// Round 5
// 126.382 us; speedup vs baseline: 1.1800x; 1.1800x over previous
//
#include <hip/hip_runtime.h>
#include <hip/hip_bf16.h>
#include <math.h>

#define B_SZ 16
#define L_SEQ 128
#define D_M 32
#define N_ST 8
#define HW 65536           // 256*256
#define NROWS (B_SZ * 128) // 2048 (b,c) rows
#define NCHUNK 2           // chunks per row for kmax (R3 config)

typedef float vfloat4 __attribute__((ext_vector_type(4)));

// Device-global scratch
__device__ float g_part[NROWS * NCHUNK];       // partial maxima
__device__ float g_y0[B_SZ * D_M * L_SEQ];     // forward branch y, fwd orientation
__device__ float g_y1[B_SZ * D_M * L_SEQ];     // backward branch y, already flipped back

__device__ __forceinline__ float silu_acc(float x) {
    return x / (1.f + expf(-x));
}
__device__ __forceinline__ float softplusf(float x) {
    return (x > 20.f) ? x : log1pf(expf(x));
}

// 8-lane sum via DPP (no LDS): xor1, xor2 within quad, then half-row mirror.
__device__ __forceinline__ float sum8_dpp(float y) {
    float t;
    t = __int_as_float(__builtin_amdgcn_mov_dpp(__float_as_int(y), 0xB1, 0xF, 0xF, true));  // quad_perm [1,0,3,2]
    y += t;
    t = __int_as_float(__builtin_amdgcn_mov_dpp(__float_as_int(y), 0x4E, 0xF, 0xF, true));  // quad_perm [2,3,0,1]
    y += t;
    t = __int_as_float(__builtin_amdgcn_mov_dpp(__float_as_int(y), 0x141, 0xF, 0xF, true)); // row_half_mirror
    y += t;
    return y;
}

// ---------------- K1: partial max over half-rows (R3 config) ----------------
__global__ __launch_bounds__(256) void kmax(const float* __restrict__ x) {
    const int blk = blockIdx.x;                 // 0..4095
    const vfloat4* __restrict__ p =
        reinterpret_cast<const vfloat4*>(x) + (size_t)blk * 8192;
    const int t = threadIdx.x;
    float m0 = -INFINITY, m1 = -INFINITY, m2 = -INFINITY, m3 = -INFINITY;
#pragma unroll
    for (int i = 0; i < 8192; i += 1024) {
        vfloat4 v0 = __builtin_nontemporal_load(p + i + t);
        vfloat4 v1 = __builtin_nontemporal_load(p + i + t + 256);
        vfloat4 v2 = __builtin_nontemporal_load(p + i + t + 512);
        vfloat4 v3 = __builtin_nontemporal_load(p + i + t + 768);
        m0 = fmaxf(m0, fmaxf(fmaxf(v0.x, v0.y), fmaxf(v0.z, v0.w)));
        m1 = fmaxf(m1, fmaxf(fmaxf(v1.x, v1.y), fmaxf(v1.z, v1.w)));
        m2 = fmaxf(m2, fmaxf(fmaxf(v2.x, v2.y), fmaxf(v2.z, v2.w)));
        m3 = fmaxf(m3, fmaxf(fmaxf(v3.x, v3.y), fmaxf(v3.z, v3.w)));
    }
    float m = fmaxf(fmaxf(m0, m1), fmaxf(m2, m3));
#pragma unroll
    for (int off = 32; off >= 1; off >>= 1)
        m = fmaxf(m, __shfl_xor(m, off));
    __shared__ float sm[4];
    if ((threadIdx.x & 63) == 0) sm[threadIdx.x >> 6] = m;
    __syncthreads();
    if (threadIdx.x == 0)
        g_part[blk] = fmaxf(fmaxf(sm[0], sm[1]), fmaxf(sm[2], sm[3]));
}

__device__ __forceinline__ float row_max(int row) {
    const int r2 = row * NCHUNK;
    return fmaxf(g_part[r2], g_part[r2 + 1]);
}

// Compute h[0..31] = LN(s*w1+b1) entirely in registers (weights = scalar loads).
__device__ __forceinline__ void compute_h(int row, const float* __restrict__ w1,
                                          const float* __restrict__ b1,
                                          const float* __restrict__ lng,
                                          const float* __restrict__ lnb,
                                          float h[D_M]) {
    const float s = row_max(row);
    float mean = 0.f;
#pragma unroll
    for (int d = 0; d < D_M; d++) { h[d] = s * w1[d] + b1[d]; mean += h[d]; }
    mean *= (1.f / D_M);
    float var = 0.f;
#pragma unroll
    for (int d = 0; d < D_M; d++) { float t = h[d] - mean; var += t * t; }
    var *= (1.f / D_M);
    const float rs = rsqrtf(var + 1e-5f);
#pragma unroll
    for (int d = 0; d < D_M; d++) h[d] = (h[d] - mean) * rs * lng[d] + lnb[d];
}

// ---------------- K2: per (batch, direction) ----------------
// LDS word map (total 15360 = 61.4 KB):
//  [0,4352)      sx  [32][136]  front pad 4 (zeros), data at +4    / sdl overlay [128][33]
//  [4352,8576)   su  [32][132]
//  [8576,12800)  sy  [32][132]
//  [12800,13056) sdt [128][2]
//  [13056,14208) sB  [128][9]
//  [14208,15360) sC  [128][9]
__global__ __launch_bounds__(512) void kbranch(
    const float* __restrict__ w1,  const float* __restrict__ b1,
    const float* __restrict__ lng, const float* __restrict__ lnb,
    const float* __restrict__ Win,
    const float* __restrict__ cw_f, const float* __restrict__ cb_f,
    const float* __restrict__ xp_f, const float* __restrict__ dtw_f,
    const float* __restrict__ dtb_f, const float* __restrict__ Al_f,
    const float* __restrict__ Dp_f,
    const float* __restrict__ cw_b, const float* __restrict__ cb_b,
    const float* __restrict__ xp_b, const float* __restrict__ dtw_b,
    const float* __restrict__ dtb_b, const float* __restrict__ Al_b,
    const float* __restrict__ Dp_b) {
    const int b = blockIdx.x >> 1;
    const int beta = blockIdx.x & 1;
    const int tid = threadIdx.x;

    const float* cw  = beta ? cw_b  : cw_f;
    const float* cb  = beta ? cb_b  : cb_f;
    const float* xp  = beta ? xp_b  : xp_f;
    const float* dtw = beta ? dtw_b : dtw_f;
    const float* dtb = beta ? dtb_b : dtb_f;
    const float* Al  = beta ? Al_b  : Al_f;
    const float* Dp  = beta ? Dp_b  : Dp_f;
    float* yout = beta ? g_y1 : g_y0;

    __shared__ __align__(16) float S[15360];
    float* sx  = S;            // [32][136], data offset +4
    float* sdl = S;            // [128][33] overlay (after conv done)
    float* su  = S + 4352;     // [32][132]
    float* sy  = S + 8576;     // [32][132]
    float* sdt = S + 12800;    // [128][2]
    float* sB  = S + 13056;    // [128][9]
    float* sC  = S + 14208;    // [128][9]

    const int l = tid & 127;
    const int q = tid >> 7;    // quarter 0..3

    // Phase 1: zero conv front-pad; compute h in registers (4x redundant, cheap)
    if (tid < 128) sx[(tid >> 2) * 136 + (tid & 3)] = 0.f;
    float h[D_M];
    compute_h(b * L_SEQ + l, w1, b1, lng, lnb, h);

    // Phase 2: x-half GEMV, weights via uniform scalar loads; store pre-flipped
    {
        const int lw = beta ? (127 - l) : l;
#pragma unroll
        for (int k = 0; k < 8; k++) {
            const int e = q * 8 + k;
            float acc = 0.f;
#pragma unroll
            for (int d = 0; d < D_M; d++) acc += h[d] * Win[e * 32 + d];
            sx[e * 136 + 4 + lw] = acc;
        }
    }
    __syncthreads();

    // Phase 3: causal depthwise conv(4) + SiLU, vectorized b128 reads
    {
        const int d = tid >> 4;          // 0..31
        const int l0 = (tid & 15) * 8;   // 0,8,...,120
        const vfloat4* px = reinterpret_cast<const vfloat4*>(sx + d * 136 + l0);
        vfloat4 a0 = px[0], a1 = px[1], a2 = px[2];
        float xv[12] = {a0.x,a0.y,a0.z,a0.w, a1.x,a1.y,a1.z,a1.w, a2.x,a2.y,a2.z,a2.w};
        const float c0 = cw[d*4+0], c1 = cw[d*4+1], c2 = cw[d*4+2], c3 = cw[d*4+3];
        const float cbd = cb[d];
        float uo[8];
#pragma unroll
        for (int j = 0; j < 8; j++) {
            float acc = cbd + c0*xv[j+1] + c1*xv[j+2] + c2*xv[j+3] + c3*xv[j+4];
            uo[j] = silu_acc(acc);
        }
        vfloat4* pu = reinterpret_cast<vfloat4*>(su + d * 132 + l0);
        vfloat4 w0 = {uo[0],uo[1],uo[2],uo[3]}, w1v = {uo[4],uo[5],uo[6],uo[7]};
        pu[0] = w0; pu[1] = w1v;
    }
    __syncthreads();

    // Phase 4: x_dbl = u^T @ xp^T; u column in regs, xp via scalar loads
    {
        float ul[D_M];
#pragma unroll
        for (int d = 0; d < D_M; d++) ul[d] = su[d * 132 + l];
        const int r0 = (q < 3) ? q * 5 : 15;
        const int nr = (q < 3) ? 5 : 3;
        for (int j = 0; j < nr; j++) {
            const int r = r0 + j;
            float acc = 0.f;
#pragma unroll
            for (int d = 0; d < D_M; d++) acc += ul[d] * xp[r * 32 + d];
            if (r < 2)       sdt[l * 2 + r] = acc;
            else if (r < 10) sB[l * 9 + (r - 2)] = acc;
            else             sC[l * 9 + (r - 10)] = acc;
        }
    }
    __syncthreads();

    // Phase 5: delta = softplus(dt @ dtw^T + dtb), overlays sx
    {
        const float dt0 = sdt[l * 2 + 0], dt1 = sdt[l * 2 + 1];
        const int d0 = q * 8;
#pragma unroll
        for (int j = 0; j < 8; j++) {
            const int d = d0 + j;
            const float t = dt0 * dtw[d * 2 + 0] + dt1 * dtw[d * 2 + 1] + dtb[d];
            sdl[l * 33 + d] = softplusf(t);
        }
    }
    __syncthreads();

    // Phase 6: sequential scan, thread=(d,n), software-pipelined operand loads
    if (tid < 256) {
        const int d = tid >> 3, n = tid & 7;
        const float A = -expf(Al[d * 8 + n]);
        const float Dd = Dp[d];
        float hst = 0.f;
        float dl = sdl[d], ul = su[d * 132], Bv = sB[n], Cv = sC[n];
        for (int ll = 0; ll < L_SEQ; ll++) {
            float dl_n = 0.f, ul_n = 0.f, Bv_n = 0.f, Cv_n = 0.f;
            if (ll < 127) {
                dl_n = sdl[(ll + 1) * 33 + d];
                ul_n = su[d * 132 + ll + 1];
                Bv_n = sB[(ll + 1) * 9 + n];
                Cv_n = sC[(ll + 1) * 9 + n];
            }
            const float dA = expf(dl * A);
            hst = dA * hst + (dl * ul) * Bv;
            const float y = sum8_dpp(hst * Cv);
            if (n == 0) sy[d * 132 + ll] = y + Dd * ul;
            dl = dl_n; ul = ul_n; Bv = Bv_n; Cv = Cv_n;
        }
    }
    __syncthreads();

    // Phase 7: store y (backward branch flipped back)
    for (int i = tid; i < 4096; i += 512) {
        const int d = i >> 7, li = i & 127;
        const int gl = beta ? (127 - li) : li;
        yout[(b * D_M + d) * L_SEQ + gl] = sy[d * 132 + li];
    }
}

// ---------------- K3: zero-LDS final ----------------
__global__ __launch_bounds__(128) void kfinal(
    const float* __restrict__ w1,  const float* __restrict__ b1,
    const float* __restrict__ lng, const float* __restrict__ lnb,
    const float* __restrict__ Win,
    const float* __restrict__ ng,  const float* __restrict__ nb,
    const float* __restrict__ Wout, const float* __restrict__ w2,
    const float* __restrict__ b2,  float* __restrict__ out) {
    const int b = blockIdx.x;
    const int l = threadIdx.x;

    float h[D_M];
    compute_h(b * L_SEQ + l, w1, b1, lng, lnb, h);

    // v[d] = (y_f + y_b)[d][l] * silu(z[d]); z = h @ Wz^T (scalar-load weights)
    float v[D_M];
#pragma unroll
    for (int d = 0; d < D_M; d++) {
        float z = 0.f;
#pragma unroll
        for (int k = 0; k < D_M; k++) z += h[k] * Win[(32 + d) * 32 + k];
        const float yc = g_y0[(b * D_M + d) * L_SEQ + l] +
                         g_y1[(b * D_M + d) * L_SEQ + l];
        v[d] = yc * silu_acc(z);
    }

    // LN / 2
    float mean = 0.f;
#pragma unroll
    for (int d = 0; d < D_M; d++) mean += v[d];
    mean *= (1.f / D_M);
    float var = 0.f;
#pragma unroll
    for (int d = 0; d < D_M; d++) { float t = v[d] - mean; var += t * t; }
    var *= (1.f / D_M);
    const float rs = rsqrtf(var + 1e-5f);
#pragma unroll
    for (int d = 0; d < D_M; d++)
        v[d] = ((v[d] - mean) * rs * ng[d] + nb[d]) * 0.5f;

    // out_proj then w2 dot, sigmoid (all scalar-load weights)
    float acc = 0.f;
    for (int o = 0; o < D_M; o++) {
        float t = 0.f;
#pragma unroll
        for (int d = 0; d < D_M; d++) t += v[d] * Wout[o * 32 + d];
        acc += t * w2[o];
    }
    acc += b2[0];
    out[b * L_SEQ + l] = 1.f / (1.f + expf(-acc));
}

extern "C" void kernel_launch(void* const* d_in, const int* in_sizes, int n_in,
                              void* d_out, int out_size, void* d_ws, size_t ws_size,
                              hipStream_t stream) {
    const float* x        = (const float*)d_in[0];
    const float* w1       = (const float*)d_in[1];
    const float* b1       = (const float*)d_in[2];
    const float* ln_g     = (const float*)d_in[3];
    const float* ln_b     = (const float*)d_in[4];
    const float* in_proj  = (const float*)d_in[5];
    const float* cw_f     = (const float*)d_in[6];
    const float* cb_f     = (const float*)d_in[7];
    const float* xp_f     = (const float*)d_in[8];
    const float* dtw_f    = (const float*)d_in[9];
    const float* dtb_f    = (const float*)d_in[10];
    const float* Al_f     = (const float*)d_in[11];
    const float* Dp_f     = (const float*)d_in[12];
    const float* cw_b     = (const float*)d_in[13];
    const float* cb_b     = (const float*)d_in[14];
    const float* xp_b     = (const float*)d_in[15];
    const float* dtw_b    = (const float*)d_in[16];
    const float* dtb_b    = (const float*)d_in[17];
    const float* Al_b     = (const float*)d_in[18];
    const float* Dp_b     = (const float*)d_in[19];
    const float* norm_g   = (const float*)d_in[20];
    const float* norm_b   = (const float*)d_in[21];
    const float* Wout     = (const float*)d_in[22];
    const float* w2       = (const float*)d_in[23];
    const float* b2       = (const float*)d_in[24];

    kmax<<<NROWS * NCHUNK, 256, 0, stream>>>(x);
    kbranch<<<B_SZ * 2, 512, 0, stream>>>(w1, b1, ln_g, ln_b, in_proj,
                                          cw_f, cb_f, xp_f, dtw_f, dtb_f, Al_f, Dp_f,
                                          cw_b, cb_b, xp_b, dtw_b, dtb_b, Al_b, Dp_b);
    kfinal<<<B_SZ, 128, 0, stream>>>(w1, b1, ln_g, ln_b, in_proj,
                                     norm_g, norm_b, Wout, w2, b2, (float*)d_out);
}